// Round 13
// baseline (188.376 us; speedup 1.0000x reference)
//
#include <hip/hip_runtime.h>

// Problem constants
#define Bn  4
#define Cn  128
#define CQn 64
#define Nn  4096

typedef _Float16 h8_t __attribute__((ext_vector_type(8)));
typedef float    f32x4 __attribute__((ext_vector_type(4)));
typedef unsigned int u32;

// ws layout (bytes):
//  Qh: [B][N][64]  f16 at 0         (2 MB)
//  Kh: [B][N][64]  f16 at 2 MB      (2 MB)
//  Vg: [B][64 jt][128 c][64 pos] f16 at 4 MB (4 MB)  -- fragment-major V
//  pPart: [B][64 it][S][128 c][64 q] f32 at 8 MB   (S x 8 MB)
//  pMl:   [B][64 it][S][64 q][2]    f32 after      (S x 128 KB)

#define QKV_BYTES   8388608ull
#define PART_PER_S  8388608ull
#define ML_PER_S    131072ull

// ---------------------------------------------------------------------------
// Kernel 1: fused QKV projection. V is written FRAGMENT-MAJOR per 64-j tile:
// j stored at pos = 32h + 8g + (i&3) + 4*(i>=4), where j = 32h+4g+(i&3)+16(i>>2)
// -> each attn lane's 8-slot MFMA B-fragment is 16 contiguous bytes.
// For the proj's 4-consecutive-j group (a = j0/4): h=a>>3, qd=a&7,
// pos_base = 32h + (qd&3)*8 + (qd>>2)*4; the 4 j's land at pos_base..+3.
// ---------------------------------------------------------------------------
__global__ __launch_bounds__(256) void qkv_proj(
    const float* __restrict__ x,
    const float* __restrict__ Wq, const float* __restrict__ bq,
    const float* __restrict__ Wk, const float* __restrict__ bk,
    const float* __restrict__ Wv, const float* __restrict__ bv,
    _Float16* __restrict__ Qh, _Float16* __restrict__ Kh, _Float16* __restrict__ Vg)
{
    const int ntile = blockIdx.x;
    const int otile = blockIdx.y;
    const int b     = blockIdx.z;
    const int tid   = threadIdx.x;
    const int nbase = ntile * 64;

    __shared__ float Ws[64][132];
    __shared__ float Xs[128][68];

    const float* Wsrc; const float* bsrc; int obase;
    if (otile == 0)      { Wsrc = Wq;                     bsrc = bq;      obase = 0; }
    else if (otile == 1) { Wsrc = Wk;                     bsrc = bk;      obase = 0; }
    else                 { Wsrc = Wv + (otile - 2) * 64 * Cn;
                           bsrc = bv + (otile - 2) * 64;  obase = (otile - 2) * 64; }

    for (int u = 0; u < 8; ++u) {
        int f = tid + u * 256;
        int row = f >> 5;
        int col = (f & 31) * 4;
        *(float4*)&Ws[row][col] = *(const float4*)&Wsrc[row * Cn + col];
    }
    const float* xb = x + ((size_t)b * Cn) * Nn + nbase;
    for (int u = 0; u < 8; ++u) {
        int f = tid + u * 256;
        int c = f >> 4;
        int n = (f & 15) * 4;
        *(float4*)&Xs[c][n] = *(const float4*)&xb[(size_t)c * Nn + n];
    }
    __syncthreads();

    const int o0 = (tid >> 4) * 4;
    const int n0 = (tid & 15) * 4;
    float acc[4][4] = {};

    for (int c = 0; c < Cn; c += 4) {
        float4 w4[4], x4[4];
        for (int oo = 0; oo < 4; ++oo) w4[oo] = *(const float4*)&Ws[o0 + oo][c];
        for (int cc = 0; cc < 4; ++cc) x4[cc] = *(const float4*)&Xs[c + cc][n0];
        for (int oo = 0; oo < 4; ++oo) {
            const float* wv = (const float*)&w4[oo];
            for (int cc = 0; cc < 4; ++cc) {
                const float wsv = wv[cc];
                const float* xp = (const float*)&x4[cc];
                acc[oo][0] += wsv * xp[0];
                acc[oo][1] += wsv * xp[1];
                acc[oo][2] += wsv * xp[2];
                acc[oo][3] += wsv * xp[3];
            }
        }
    }

    float bias[4];
    for (int oo = 0; oo < 4; ++oo) bias[oo] = bsrc[o0 + oo];

    union H4 { _Float16 e[4]; short4 v; };

    if (otile <= 1) {
        _Float16* dst = (otile == 0 ? Qh : Kh) + ((size_t)b * Nn + nbase) * CQn;
        for (int nn = 0; nn < 4; ++nn) {
            H4 h;
            for (int oo = 0; oo < 4; ++oo) h.e[oo] = (_Float16)(acc[oo][nn] + bias[oo]);
            *(short4*)&dst[(size_t)(n0 + nn) * CQn + o0] = h.v;
        }
    } else {
        // Vg[b][ntile][c][pos]
        _Float16* dst = Vg + (size_t)(b * 64 + ntile) * 128 * 64;
        const int og = obase + o0;
        const int a  = n0 >> 2;
        const int h  = a >> 3, qd = a & 7;
        const int pbase = h * 32 + (qd & 3) * 8 + (qd >> 2) * 4;
        for (int oo = 0; oo < 4; ++oo) {
            H4 hh;
            for (int nn = 0; nn < 4; ++nn) hh.e[nn] = (_Float16)(acc[oo][nn] + bias[oo]);
            *(short4*)&dst[(size_t)(og + oo) * 64 + pbase] = hh.v;
        }
    }
}

// ---------------------------------------------------------------------------
// Kernel 2: MFMA flash attention, KV split across blocks (grid z = s).
// Round-13 recombination of proven halves:
//  - K: staged via global_load_lds into a 2 x 8 KB LDS double buffer
//    (round 11's schedule: stage t+1 BEFORE computing t; latency crosses
//    the single per-tile barrier). XOR-swizzled source/reads, <=2-way.
//  - V: read DIRECTLY from global in fragment-major layout (round 12's
//    zero-conflict win): one lane B-fragment = 16 contiguous bytes; the
//    32 b128 loads are issued between scores and softmax (~400 cy cover);
//    the 16 KB tile is shared by the block's 4 waves through L1 (24 KB
//    working set < 32 KB L1).
//  - LDS = 16 KB, launch_bounds(256,4) -> grid 1024 = exactly 4 blocks/CU,
//    no residency tail (round 12's 48 KB gave 3/CU + 1/CU straggler phase).
// Swapped QK^T (D=S^T, col=query=ln); kappa(e,g)=4g+(e&3)+16(e>>2) pairing.
// Defer-max (THR=8). One barrier per tile.
// ---------------------------------------------------------------------------
__device__ __forceinline__ void gload16(const void* g, void* l) {
    __builtin_amdgcn_global_load_lds(
        (const __attribute__((address_space(1))) u32*)g,
        (__attribute__((address_space(3))) u32*)l, 16, 0, 0);
}

__global__ __launch_bounds__(256, 4) void attn_split(
    const _Float16* __restrict__ Qh, const _Float16* __restrict__ Kh,
    const _Float16* __restrict__ Vg, float* __restrict__ out,
    float* __restrict__ pPart, float* __restrict__ pMl, int S)
{
    __shared__ __align__(16) char smem[16384];   // K double buffer (2 x 8 KB)

    const int tid  = threadIdx.x;
    const int w    = tid >> 6;
    const int lane = tid & 63;
    const int g    = lane >> 4;
    const int ln   = lane & 15;
    const int it   = blockIdx.x;
    const int b    = blockIdx.y;
    const int s    = blockIdx.z;
    const int wib  = it * 64 + w * 16;
    const int njt  = 64 / S;

    // Persistent Q fragments (B operand: col=ln -> query wib+ln)
    const _Float16* qrow = Qh + ((size_t)(b * Nn + wib + ln)) * CQn + 8 * g;
    const h8_t q0 = *(const h8_t*)(qrow);
    const h8_t q1 = *(const h8_t*)(qrow + 32);

    const _Float16* Kb  = Kh + (size_t)b * Nn * CQn;
    const _Float16* Vgb = Vg + (size_t)b * 64 * 8192;   // 64 tiles x 8192 f16

    // K staging source offsets (f16): LDS granule G (16B) holds
    // K_tile[row = G>>3][((G&7) ^ (row&7)) * 8 .. +7]   (row = key, 128B rows)
    int ks[2];
    #pragma unroll
    for (int u = 0; u < 2; ++u) {
        int G   = u * 256 + tid;
        int row = G >> 3;
        ks[u] = row * CQn + (((G & 7) ^ (row & 7)) * 8);
    }

    // K LDS read offsets (bytes): row = js*16+ln, granules g and 4+g, XOR r7
    const int r7  = ln & 7;
    const int kb0 = ln * 128 + (((    g) ^ r7) << 4);
    const int kb1 = ln * 128 + (((4 + g) ^ r7) << 4);

    auto stageK = [&](int koff, int jt) {
        const _Float16* src = Kb + (size_t)jt * 64 * CQn;
        #pragma unroll
        for (int u = 0; u < 2; ++u)
            gload16(src + ks[u], smem + koff + u * 4096 + w * 1024);
    };

    f32x4 oacc[8];
    #pragma unroll
    for (int i = 0; i < 8; ++i) oacc[i] = (f32x4){0.f, 0.f, 0.f, 0.f};
    float m_run = -3.0e38f, l_run = 0.f;

    const int jt0 = s * njt;
    stageK(0, jt0);
    __syncthreads();

    for (int t = 0; t < njt; ++t) {
        // 1) stage next K tile into the other buffer (drained at barrier)
        if (t + 1 < njt) stageK(((t + 1) & 1) ? 8192 : 0, jt0 + t + 1);

        // 2) scores from LDS K: st[js] rows = keys js*16+4g+r, col = query ln
        const char* KU = smem + ((t & 1) ? 8192 : 0);
        f32x4 st[4];
        __builtin_amdgcn_s_setprio(1);
        #pragma unroll
        for (int js = 0; js < 4; ++js) {
            h8_t k0 = *(const h8_t*)(KU + kb0 + js * 2048);
            h8_t k1 = *(const h8_t*)(KU + kb1 + js * 2048);
            st[js] = (f32x4){0.f, 0.f, 0.f, 0.f};
            st[js] = __builtin_amdgcn_mfma_f32_16x16x32_f16(k0, q0, st[js], 0, 0, 0);
            st[js] = __builtin_amdgcn_mfma_f32_16x16x32_f16(k1, q1, st[js], 0, 0, 0);
        }
        __builtin_amdgcn_s_setprio(0);

        // 3) V fragments direct from global (fragment-major: 16B contiguous
        //    per lane); issued here so L1/L2 latency hides under softmax.
        const _Float16* vt = Vgb + (size_t)(jt0 + t) * 8192 + (size_t)ln * 64 + 8 * g;
        h8_t vf0[8], vf1[8];
        #pragma unroll
        for (int cs = 0; cs < 8; ++cs) {
            vf0[cs] = *(const h8_t*)(vt + cs * 1024);
            vf1[cs] = *(const h8_t*)(vt + cs * 1024 + 32);
        }

        // 4) online softmax with defer-max (THR=8)
        float tmax = st[0][0];
        #pragma unroll
        for (int js = 0; js < 4; ++js)
            #pragma unroll
            for (int r = 0; r < 4; ++r) tmax = fmaxf(tmax, st[js][r]);
        tmax = fmaxf(tmax, __shfl_xor(tmax, 16));
        tmax = fmaxf(tmax, __shfl_xor(tmax, 32));
        if (__any(tmax > m_run + 8.f)) {
            const float mnew  = fmaxf(m_run, tmax);
            const float alpha = __expf(m_run - mnew);
            const float a0 = __shfl(alpha, 4 * g + 0);
            const float a1 = __shfl(alpha, 4 * g + 1);
            const float a2 = __shfl(alpha, 4 * g + 2);
            const float a3 = __shfl(alpha, 4 * g + 3);
            #pragma unroll
            for (int cs = 0; cs < 8; ++cs) {
                oacc[cs][0] *= a0; oacc[cs][1] *= a1;
                oacc[cs][2] *= a2; oacc[cs][3] *= a3;
            }
            l_run *= alpha;
            m_run = mnew;
        }
        float ts = 0.f;
        #pragma unroll
        for (int js = 0; js < 4; ++js)
            #pragma unroll
            for (int r = 0; r < 4; ++r) {
                float p = __expf(st[js][r] - m_run);
                st[js][r] = p;
                ts += p;
            }
        ts += __shfl_xor(ts, 16);
        ts += __shfl_xor(ts, 32);
        l_run += ts;

        // 5) P fragments by kappa(e,g) = 4g+(e&3)+16*(e>>2)
        union H8 { h8_t h; _Float16 e[8]; };
        H8 p0u, p1u;
        #pragma unroll
        for (int r = 0; r < 4; ++r) {
            p0u.e[r]     = (_Float16)st[0][r];
            p0u.e[4 + r] = (_Float16)st[1][r];
            p1u.e[r]     = (_Float16)st[2][r];
            p1u.e[4 + r] = (_Float16)st[3][r];
        }
        const h8_t pa0 = p0u.h;
        const h8_t pa1 = p1u.h;

        // 6) PV: fragment-major V registers, same kappa pairing
        __builtin_amdgcn_s_setprio(1);
        #pragma unroll
        for (int cs = 0; cs < 8; ++cs) {
            oacc[cs] = __builtin_amdgcn_mfma_f32_16x16x32_f16(pa0, vf0[cs], oacc[cs], 0, 0, 0);
            oacc[cs] = __builtin_amdgcn_mfma_f32_16x16x32_f16(pa1, vf1[cs], oacc[cs], 0, 0, 0);
        }
        __builtin_amdgcn_s_setprio(0);

        __syncthreads();   // drains staged K(t+1); frees K buf t
    }

    if (S == 1) {
        const float lr = 1.f / l_run;
        const float l0 = __shfl(lr, 4 * g + 0);
        const float l1 = __shfl(lr, 4 * g + 1);
        const float l2 = __shfl(lr, 4 * g + 2);
        const float l3 = __shfl(lr, 4 * g + 3);
        float* ob = out + (size_t)b * Cn * Nn;
        #pragma unroll
        for (int cs = 0; cs < 8; ++cs) {
            float4 o;
            o.x = oacc[cs][0] * l0;
            o.y = oacc[cs][1] * l1;
            o.z = oacc[cs][2] * l2;
            o.w = oacc[cs][3] * l3;
            *(float4*)&ob[(size_t)(cs * 16 + ln) * Nn + wib + 4 * g] = o;
        }
    } else {
        float* pp = pPart + (((size_t)b * 64 + it) * S + s) * 8192;
        const int qloc = w * 16 + 4 * g;
        #pragma unroll
        for (int cs = 0; cs < 8; ++cs)
            *(float4*)&pp[(size_t)(cs * 16 + ln) * 64 + qloc] =
                make_float4(oacc[cs][0], oacc[cs][1], oacc[cs][2], oacc[cs][3]);
        if (g == 0) {
            float* ml = pMl + ((((size_t)b * 64 + it) * S + s) * 64 + w * 16 + ln) * 2;
            ml[0] = m_run;
            ml[1] = l_run;
        }
    }
}

// ---------------------------------------------------------------------------
// Kernel 3: flash-combine across S splits. Grid (64 it, B), 256 threads.
// ---------------------------------------------------------------------------
__global__ __launch_bounds__(256) void attn_combine(
    const float* __restrict__ pPart, const float* __restrict__ pMl,
    float* __restrict__ out, int S)
{
    const int it  = blockIdx.x;
    const int b   = blockIdx.y;
    const int tid = threadIdx.x;

    __shared__ float wgt[4][64];
    __shared__ float linv[64];

    if (tid < 64) {
        const float* mlb = pMl + (((size_t)b * 64 + it) * S * 64 + tid) * 2;
        float ms[4], ls[4], m = -3.0e38f;
        for (int s = 0; s < S; ++s) {
            ms[s] = mlb[s * 128 + 0];
            ls[s] = mlb[s * 128 + 1];
            m = fmaxf(m, ms[s]);
        }
        float l = 0.f;
        for (int s = 0; s < S; ++s) {
            float wv = __expf(ms[s] - m);
            wgt[s][tid] = wv;
            l += wv * ls[s];
        }
        linv[tid] = 1.f / l;
    }
    __syncthreads();

    const int c  = tid >> 1;
    const int q0 = (tid & 1) * 32;
    const float* base = pPart + ((size_t)b * 64 + it) * S * 8192 + (size_t)c * 64 + q0;

    float acc[32];
    #pragma unroll
    for (int k = 0; k < 32; ++k) acc[k] = 0.f;
    for (int s = 0; s < S; ++s) {
        const float* ps = base + (size_t)s * 8192;
        #pragma unroll
        for (int k = 0; k < 32; k += 4) {
            float4 v = *(const float4*)(ps + k);
            acc[k + 0] += wgt[s][q0 + k + 0] * v.x;
            acc[k + 1] += wgt[s][q0 + k + 1] * v.y;
            acc[k + 2] += wgt[s][q0 + k + 2] * v.z;
            acc[k + 3] += wgt[s][q0 + k + 3] * v.w;
        }
    }
    float* ob = out + ((size_t)b * Cn + c) * Nn + it * 64 + q0;
    #pragma unroll
    for (int k = 0; k < 32; k += 4) {
        float4 o;
        o.x = acc[k + 0] * linv[q0 + k + 0];
        o.y = acc[k + 1] * linv[q0 + k + 1];
        o.z = acc[k + 2] * linv[q0 + k + 2];
        o.w = acc[k + 3] * linv[q0 + k + 3];
        *(float4*)&ob[k] = o;
    }
}

extern "C" void kernel_launch(void* const* d_in, const int* in_sizes, int n_in,
                              void* d_out, int out_size, void* d_ws, size_t ws_size,
                              hipStream_t stream) {
    const float* x  = (const float*)d_in[0];
    const float* Wq = (const float*)d_in[1];
    const float* bq = (const float*)d_in[2];
    const float* Wk = (const float*)d_in[3];
    const float* bk = (const float*)d_in[4];
    const float* Wv = (const float*)d_in[5];
    const float* bv = (const float*)d_in[6];
    float* out = (float*)d_out;

    _Float16* ws = (_Float16*)d_ws;
    _Float16* Qh = ws;
    _Float16* Kh = ws + 1048576;
    _Float16* Vg = ws + 2097152;

    int S = 1;
    if (ws_size >= QKV_BYTES + 4 * (PART_PER_S + ML_PER_S)) S = 4;
    else if (ws_size >= QKV_BYTES + 2 * (PART_PER_S + ML_PER_S)) S = 2;

    float* pPart = (float*)((char*)d_ws + QKV_BYTES);
    float* pMl   = (float*)((char*)d_ws + QKV_BYTES + (size_t)S * PART_PER_S);

    dim3 gproj(Nn / 64, 4, Bn);
    qkv_proj<<<gproj, 256, 0, stream>>>(x, Wq, bq, Wk, bk, Wv, bv, Qh, Kh, Vg);

    dim3 gattn(Nn / 64, Bn, S);
    attn_split<<<gattn, 256, 0, stream>>>(Qh, Kh, Vg, out, pPart, pMl, S);

    if (S > 1) {
        dim3 gcomb(Nn / 64, Bn);
        attn_combine<<<gcomb, 256, 0, stream>>>(pPart, pMl, out, S);
    }
}

// Round 14
// 88.375 us; speedup vs baseline: 2.1315x; 2.1315x over previous
//
#include <hip/hip_runtime.h>

// Problem constants
#define Bn  4
#define Cn  128
#define CQn 64
#define Nn  4096

typedef _Float16 h8_t __attribute__((ext_vector_type(8)));
typedef float    f32x4 __attribute__((ext_vector_type(4)));
typedef unsigned int u32;

// ws layout (bytes):
//  Qh: [B][N][64]  f16 at 0         (2 MB)
//  Kh: [B][N][64]  f16 at 2 MB      (2 MB)
//  Vg: [B][64 jt][128 c][64 pos] f16 at 4 MB (4 MB)  -- fragment-major V
//  pPart: [B][64 it][S][128 c][64 q] f32 at 8 MB   (S x 8 MB)
//  pMl:   [B][64 it][S][64 q][2]    f32 after      (S x 128 KB)

#define QKV_BYTES   8388608ull
#define PART_PER_S  8388608ull
#define ML_PER_S    131072ull

// ---------------------------------------------------------------------------
// Kernel 1: fused QKV projection. V is written FRAGMENT-MAJOR per 64-j tile:
// j stored at pos = 32h + 8g + (i&3) + 4*(i>=4), where j = 32h+4g+(i&3)+16(i>>2)
// -> each attn lane's 8-slot MFMA B-fragment is 16 contiguous bytes.
// ---------------------------------------------------------------------------
__global__ __launch_bounds__(256) void qkv_proj(
    const float* __restrict__ x,
    const float* __restrict__ Wq, const float* __restrict__ bq,
    const float* __restrict__ Wk, const float* __restrict__ bk,
    const float* __restrict__ Wv, const float* __restrict__ bv,
    _Float16* __restrict__ Qh, _Float16* __restrict__ Kh, _Float16* __restrict__ Vg)
{
    const int ntile = blockIdx.x;
    const int otile = blockIdx.y;
    const int b     = blockIdx.z;
    const int tid   = threadIdx.x;
    const int nbase = ntile * 64;

    __shared__ float Ws[64][132];
    __shared__ float Xs[128][68];

    const float* Wsrc; const float* bsrc; int obase;
    if (otile == 0)      { Wsrc = Wq;                     bsrc = bq;      obase = 0; }
    else if (otile == 1) { Wsrc = Wk;                     bsrc = bk;      obase = 0; }
    else                 { Wsrc = Wv + (otile - 2) * 64 * Cn;
                           bsrc = bv + (otile - 2) * 64;  obase = (otile - 2) * 64; }

    for (int u = 0; u < 8; ++u) {
        int f = tid + u * 256;
        int row = f >> 5;
        int col = (f & 31) * 4;
        *(float4*)&Ws[row][col] = *(const float4*)&Wsrc[row * Cn + col];
    }
    const float* xb = x + ((size_t)b * Cn) * Nn + nbase;
    for (int u = 0; u < 8; ++u) {
        int f = tid + u * 256;
        int c = f >> 4;
        int n = (f & 15) * 4;
        *(float4*)&Xs[c][n] = *(const float4*)&xb[(size_t)c * Nn + n];
    }
    __syncthreads();

    const int o0 = (tid >> 4) * 4;
    const int n0 = (tid & 15) * 4;
    float acc[4][4] = {};

    for (int c = 0; c < Cn; c += 4) {
        float4 w4[4], x4[4];
        for (int oo = 0; oo < 4; ++oo) w4[oo] = *(const float4*)&Ws[o0 + oo][c];
        for (int cc = 0; cc < 4; ++cc) x4[cc] = *(const float4*)&Xs[c + cc][n0];
        for (int oo = 0; oo < 4; ++oo) {
            const float* wv = (const float*)&w4[oo];
            for (int cc = 0; cc < 4; ++cc) {
                const float wsv = wv[cc];
                const float* xp = (const float*)&x4[cc];
                acc[oo][0] += wsv * xp[0];
                acc[oo][1] += wsv * xp[1];
                acc[oo][2] += wsv * xp[2];
                acc[oo][3] += wsv * xp[3];
            }
        }
    }

    float bias[4];
    for (int oo = 0; oo < 4; ++oo) bias[oo] = bsrc[o0 + oo];

    union H4 { _Float16 e[4]; short4 v; };

    if (otile <= 1) {
        _Float16* dst = (otile == 0 ? Qh : Kh) + ((size_t)b * Nn + nbase) * CQn;
        for (int nn = 0; nn < 4; ++nn) {
            H4 h;
            for (int oo = 0; oo < 4; ++oo) h.e[oo] = (_Float16)(acc[oo][nn] + bias[oo]);
            *(short4*)&dst[(size_t)(n0 + nn) * CQn + o0] = h.v;
        }
    } else {
        // Vg[b][ntile][c][pos]
        _Float16* dst = Vg + (size_t)(b * 64 + ntile) * 128 * 64;
        const int og = obase + o0;
        const int a  = n0 >> 2;
        const int h  = a >> 3, qd = a & 7;
        const int pbase = h * 32 + (qd & 3) * 8 + (qd >> 2) * 4;
        for (int oo = 0; oo < 4; ++oo) {
            H4 hh;
            for (int nn = 0; nn < 4; ++nn) hh.e[nn] = (_Float16)(acc[oo][nn] + bias[oo]);
            *(short4*)&dst[(size_t)(og + oo) * 64 + pbase] = hh.v;
        }
    }
}

// ---------------------------------------------------------------------------
// Kernel 2: MFMA flash attention, KV split across blocks (grid z = s).
// 13-round allocator model: VGPR budget = 512 / (waves/EU at the max
// occupancy implied by STATIC LDS + block size); launch_bounds arg 2 and
// waves_per_eu never raise it. So: LDS = 40 KB (K single 8 KB + V dbuf
// 2x16 KB) -> exactly 4 blocks/CU (grid 1024, zero tail) AND a 128-VGPR
// budget; register demand ~85 -> no spill (R13's 16 KB gave a 64-cap and
// 50 MB of spill).
//  - K: global_load_lds staged, XOR-swizzled, b128 reads (R11's clean path)
//  - V: fragment-major (R12: 0 bank conflicts), staged via global_load_lds,
//    one b128 per (cs,half) at the MFMA.
// Schedule/tile: scores -> barrier#1 (K free) -> issue K(t+1)+V(t+1) async
// -> softmax+PV cover latency -> barrier#2 (vmcnt drain).
// Swapped QK^T (D=S^T, col=query=ln); kappa(e,g)=4g+(e&3)+16(e>>2) pairing.
// Defer-max (THR=8).
// ---------------------------------------------------------------------------
__device__ __forceinline__ void gload16(const void* g, void* l) {
    __builtin_amdgcn_global_load_lds(
        (const __attribute__((address_space(1))) u32*)g,
        (__attribute__((address_space(3))) u32*)l, 16, 0, 0);
}

#define KOFF  0          // K buffer: 8 KB (single)
#define VOFF0 8192       // V buffer 0: 16 KB
#define VOFF1 24576      // V buffer 1: 16 KB

__global__ __launch_bounds__(256) void attn_split(
    const _Float16* __restrict__ Qh, const _Float16* __restrict__ Kh,
    const _Float16* __restrict__ Vg, float* __restrict__ out,
    float* __restrict__ pPart, float* __restrict__ pMl, int S)
{
    __shared__ __align__(16) char smem[40960];

    const int tid  = threadIdx.x;
    const int w    = tid >> 6;
    const int lane = tid & 63;
    const int g    = lane >> 4;
    const int ln   = lane & 15;
    const int it   = blockIdx.x;
    const int b    = blockIdx.y;
    const int s    = blockIdx.z;
    const int wib  = it * 64 + w * 16;
    const int njt  = 64 / S;

    // Persistent Q fragments (B operand: col=ln -> query wib+ln)
    const _Float16* qrow = Qh + ((size_t)(b * Nn + wib + ln)) * CQn + 8 * g;
    const h8_t q0 = *(const h8_t*)(qrow);
    const h8_t q1 = *(const h8_t*)(qrow + 32);

    const _Float16* Kb  = Kh + (size_t)b * Nn * CQn;
    const _Float16* Vgb = Vg + (size_t)b * 64 * 8192;   // 64 tiles x 8192 f16

    // K staging source offsets (f16): granule G holds
    // K_tile[row=G>>3][((G&7)^(row&7))*8 .. +7]
    int ks[2];
    #pragma unroll
    for (int u = 0; u < 2; ++u) {
        int G   = u * 256 + tid;
        int row = G >> 3;
        ks[u] = row * CQn + (((G & 7) ^ (row & 7)) * 8);
    }
    // V staging source offsets (f16), fragment-major tile [128c][64pos]
    int vs[4];
    #pragma unroll
    for (int u = 0; u < 4; ++u) {
        int G   = u * 256 + tid;
        int row = G >> 3;
        vs[u] = row * 64 + (((G & 7) ^ (row & 7)) * 8);
    }

    // LDS read offsets (bytes), XOR r7 = ln&7
    const int r7  = ln & 7;
    const int kb0 = ln * 128 + (((    g) ^ r7) << 4);
    const int kb1 = ln * 128 + (((4 + g) ^ r7) << 4);
    const int vb0 = kb0;                       // same formula, V rows cs*16+ln
    const int vb1 = kb1;

    auto stageK = [&](int jt) {
        const _Float16* src = Kb + (size_t)jt * 64 * CQn;
        #pragma unroll
        for (int u = 0; u < 2; ++u)
            gload16(src + ks[u], smem + KOFF + u * 4096 + w * 1024);
    };
    auto stageV = [&](int voff, int jt) {
        const _Float16* src = Vgb + (size_t)jt * 8192;
        #pragma unroll
        for (int u = 0; u < 4; ++u)
            gload16(src + vs[u], smem + voff + u * 4096 + w * 1024);
    };

    f32x4 oacc[8];
    #pragma unroll
    for (int i = 0; i < 8; ++i) oacc[i] = (f32x4){0.f, 0.f, 0.f, 0.f};
    float m_run = -3.0e38f, l_run = 0.f;

    const int jt0 = s * njt;
    stageK(jt0);
    stageV(VOFF0, jt0);
    __syncthreads();

    for (int t = 0; t < njt; ++t) {
        // 1) scores from K LDS: st[js] rows = keys js*16+4g+r, col = query ln
        f32x4 st[4];
        __builtin_amdgcn_s_setprio(1);
        #pragma unroll
        for (int js = 0; js < 4; ++js) {
            h8_t k0 = *(const h8_t*)(smem + KOFF + kb0 + js * 2048);
            h8_t k1 = *(const h8_t*)(smem + KOFF + kb1 + js * 2048);
            st[js] = (f32x4){0.f, 0.f, 0.f, 0.f};
            st[js] = __builtin_amdgcn_mfma_f32_16x16x32_f16(k0, q0, st[js], 0, 0, 0);
            st[js] = __builtin_amdgcn_mfma_f32_16x16x32_f16(k1, q1, st[js], 0, 0, 0);
        }
        __builtin_amdgcn_s_setprio(0);

        __syncthreads();   // #1: all waves done reading K buffer

        // 2) stage next tile (K into same buffer, V into other buffer);
        //    latency hides under softmax + PV below.
        if (t + 1 < njt) {
            stageK(jt0 + t + 1);
            stageV(((t + 1) & 1) ? VOFF1 : VOFF0, jt0 + t + 1);
        }

        // 3) online softmax with defer-max (THR=8)
        float tmax = st[0][0];
        #pragma unroll
        for (int js = 0; js < 4; ++js)
            #pragma unroll
            for (int r = 0; r < 4; ++r) tmax = fmaxf(tmax, st[js][r]);
        tmax = fmaxf(tmax, __shfl_xor(tmax, 16));
        tmax = fmaxf(tmax, __shfl_xor(tmax, 32));
        if (__any(tmax > m_run + 8.f)) {
            const float mnew  = fmaxf(m_run, tmax);
            const float alpha = __expf(m_run - mnew);
            const float a0 = __shfl(alpha, 4 * g + 0);
            const float a1 = __shfl(alpha, 4 * g + 1);
            const float a2 = __shfl(alpha, 4 * g + 2);
            const float a3 = __shfl(alpha, 4 * g + 3);
            #pragma unroll
            for (int cs = 0; cs < 8; ++cs) {
                oacc[cs][0] *= a0; oacc[cs][1] *= a1;
                oacc[cs][2] *= a2; oacc[cs][3] *= a3;
            }
            l_run *= alpha;
            m_run = mnew;
        }
        float ts = 0.f;
        #pragma unroll
        for (int js = 0; js < 4; ++js)
            #pragma unroll
            for (int r = 0; r < 4; ++r) {
                float p = __expf(st[js][r] - m_run);
                st[js][r] = p;
                ts += p;
            }
        ts += __shfl_xor(ts, 16);
        ts += __shfl_xor(ts, 32);
        l_run += ts;

        // 4) P fragments by kappa(e,g) = 4g+(e&3)+16*(e>>2)
        union H8 { h8_t h; _Float16 e[8]; };
        H8 p0u, p1u;
        #pragma unroll
        for (int r = 0; r < 4; ++r) {
            p0u.e[r]     = (_Float16)st[0][r];
            p0u.e[4 + r] = (_Float16)st[1][r];
            p1u.e[r]     = (_Float16)st[2][r];
            p1u.e[4 + r] = (_Float16)st[3][r];
        }
        const h8_t pa0 = p0u.h;
        const h8_t pa1 = p1u.h;

        // 5) PV: fragment-major V from LDS, one b128 per (cs, half)
        const char* VU = smem + ((t & 1) ? VOFF1 : VOFF0);
        __builtin_amdgcn_s_setprio(1);
        #pragma unroll
        for (int cs = 0; cs < 8; ++cs) {
            h8_t v01 = *(const h8_t*)(VU + vb0 + cs * 2048);
            h8_t v23 = *(const h8_t*)(VU + vb1 + cs * 2048);
            oacc[cs] = __builtin_amdgcn_mfma_f32_16x16x32_f16(pa0, v01, oacc[cs], 0, 0, 0);
            oacc[cs] = __builtin_amdgcn_mfma_f32_16x16x32_f16(pa1, v23, oacc[cs], 0, 0, 0);
        }
        __builtin_amdgcn_s_setprio(0);

        __syncthreads();   // #2: drains staged K/V(t+1); frees V buf t
    }

    if (S == 1) {
        const float lr = 1.f / l_run;
        const float l0 = __shfl(lr, 4 * g + 0);
        const float l1 = __shfl(lr, 4 * g + 1);
        const float l2 = __shfl(lr, 4 * g + 2);
        const float l3 = __shfl(lr, 4 * g + 3);
        float* ob = out + (size_t)b * Cn * Nn;
        #pragma unroll
        for (int cs = 0; cs < 8; ++cs) {
            float4 o;
            o.x = oacc[cs][0] * l0;
            o.y = oacc[cs][1] * l1;
            o.z = oacc[cs][2] * l2;
            o.w = oacc[cs][3] * l3;
            *(float4*)&ob[(size_t)(cs * 16 + ln) * Nn + wib + 4 * g] = o;
        }
    } else {
        float* pp = pPart + (((size_t)b * 64 + it) * S + s) * 8192;
        const int qloc = w * 16 + 4 * g;
        #pragma unroll
        for (int cs = 0; cs < 8; ++cs)
            *(float4*)&pp[(size_t)(cs * 16 + ln) * 64 + qloc] =
                make_float4(oacc[cs][0], oacc[cs][1], oacc[cs][2], oacc[cs][3]);
        if (g == 0) {
            float* ml = pMl + ((((size_t)b * 64 + it) * S + s) * 64 + w * 16 + ln) * 2;
            ml[0] = m_run;
            ml[1] = l_run;
        }
    }
}

// ---------------------------------------------------------------------------
// Kernel 3: flash-combine across S splits. Grid (64 it, B), 256 threads.
// ---------------------------------------------------------------------------
__global__ __launch_bounds__(256) void attn_combine(
    const float* __restrict__ pPart, const float* __restrict__ pMl,
    float* __restrict__ out, int S)
{
    const int it  = blockIdx.x;
    const int b   = blockIdx.y;
    const int tid = threadIdx.x;

    __shared__ float wgt[4][64];
    __shared__ float linv[64];

    if (tid < 64) {
        const float* mlb = pMl + (((size_t)b * 64 + it) * S * 64 + tid) * 2;
        float ms[4], ls[4], m = -3.0e38f;
        for (int s = 0; s < S; ++s) {
            ms[s] = mlb[s * 128 + 0];
            ls[s] = mlb[s * 128 + 1];
            m = fmaxf(m, ms[s]);
        }
        float l = 0.f;
        for (int s = 0; s < S; ++s) {
            float wv = __expf(ms[s] - m);
            wgt[s][tid] = wv;
            l += wv * ls[s];
        }
        linv[tid] = 1.f / l;
    }
    __syncthreads();

    const int c  = tid >> 1;
    const int q0 = (tid & 1) * 32;
    const float* base = pPart + ((size_t)b * 64 + it) * S * 8192 + (size_t)c * 64 + q0;

    float acc[32];
    #pragma unroll
    for (int k = 0; k < 32; ++k) acc[k] = 0.f;
    for (int s = 0; s < S; ++s) {
        const float* ps = base + (size_t)s * 8192;
        #pragma unroll
        for (int k = 0; k < 32; k += 4) {
            float4 v = *(const float4*)(ps + k);
            acc[k + 0] += wgt[s][q0 + k + 0] * v.x;
            acc[k + 1] += wgt[s][q0 + k + 1] * v.y;
            acc[k + 2] += wgt[s][q0 + k + 2] * v.z;
            acc[k + 3] += wgt[s][q0 + k + 3] * v.w;
        }
    }
    float* ob = out + ((size_t)b * Cn + c) * Nn + it * 64 + q0;
    #pragma unroll
    for (int k = 0; k < 32; k += 4) {
        float4 o;
        o.x = acc[k + 0] * linv[q0 + k + 0];
        o.y = acc[k + 1] * linv[q0 + k + 1];
        o.z = acc[k + 2] * linv[q0 + k + 2];
        o.w = acc[k + 3] * linv[q0 + k + 3];
        *(float4*)&ob[k] = o;
    }
}

extern "C" void kernel_launch(void* const* d_in, const int* in_sizes, int n_in,
                              void* d_out, int out_size, void* d_ws, size_t ws_size,
                              hipStream_t stream) {
    const float* x  = (const float*)d_in[0];
    const float* Wq = (const float*)d_in[1];
    const float* bq = (const float*)d_in[2];
    const float* Wk = (const float*)d_in[3];
    const float* bk = (const float*)d_in[4];
    const float* Wv = (const float*)d_in[5];
    const float* bv = (const float*)d_in[6];
    float* out = (float*)d_out;

    _Float16* ws = (_Float16*)d_ws;
    _Float16* Qh = ws;
    _Float16* Kh = ws + 1048576;
    _Float16* Vg = ws + 2097152;

    int S = 1;
    if (ws_size >= QKV_BYTES + 4 * (PART_PER_S + ML_PER_S)) S = 4;
    else if (ws_size >= QKV_BYTES + 2 * (PART_PER_S + ML_PER_S)) S = 2;

    float* pPart = (float*)((char*)d_ws + QKV_BYTES);
    float* pMl   = (float*)((char*)d_ws + QKV_BYTES + (size_t)S * PART_PER_S);

    dim3 gproj(Nn / 64, 4, Bn);
    qkv_proj<<<gproj, 256, 0, stream>>>(x, Wq, bq, Wk, bk, Wv, bv, Qh, Kh, Vg);

    dim3 gattn(Nn / 64, Bn, S);
    attn_split<<<gattn, 256, 0, stream>>>(Qh, Kh, Vg, out, pPart, pMl, S);

    if (S > 1) {
        dim3 gcomb(Nn / 64, Bn);
        attn_combine<<<gcomb, 256, 0, stream>>>(pPart, pMl, out, S);
    }
}

// Round 15
// 86.243 us; speedup vs baseline: 2.1843x; 1.0247x over previous
//
#include <hip/hip_runtime.h>

// Problem constants
#define Bn  4
#define Cn  128
#define CQn 64
#define Nn  4096

typedef _Float16 h8_t __attribute__((ext_vector_type(8)));
typedef float    f32x4 __attribute__((ext_vector_type(4)));
typedef unsigned int u32;

// ws layout (bytes):
//  Qh: [B][N][64]  f16 at 0         (2 MB)
//  Kh: [B][N][64]  f16 at 2 MB      (2 MB)
//  Vg: [B][64 jt][128 c][64 pos] f16 at 4 MB (4 MB)  -- fragment-major V
//  pPart: [B][64 it][S][128 c][64 q] f32 at 8 MB   (S x 8 MB)
//  pMl:   [B][64 it][S][64 q][2]    f32 after      (S x 128 KB)

#define QKV_BYTES   8388608ull
#define PART_PER_S  8388608ull
#define ML_PER_S    131072ull

// ---------------------------------------------------------------------------
// Kernel 1: fused QKV projection. V is written FRAGMENT-MAJOR per 64-j tile:
// j stored at pos = 32h + 8g + (i&3) + 4*(i>=4), where j = 32h+4g+(i&3)+16(i>>2)
// -> each attn lane's 8-slot MFMA B-fragment is 16 contiguous bytes.
// ---------------------------------------------------------------------------
__global__ __launch_bounds__(256) void qkv_proj(
    const float* __restrict__ x,
    const float* __restrict__ Wq, const float* __restrict__ bq,
    const float* __restrict__ Wk, const float* __restrict__ bk,
    const float* __restrict__ Wv, const float* __restrict__ bv,
    _Float16* __restrict__ Qh, _Float16* __restrict__ Kh, _Float16* __restrict__ Vg)
{
    const int ntile = blockIdx.x;
    const int otile = blockIdx.y;
    const int b     = blockIdx.z;
    const int tid   = threadIdx.x;
    const int nbase = ntile * 64;

    __shared__ float Ws[64][132];
    __shared__ float Xs[128][68];

    const float* Wsrc; const float* bsrc; int obase;
    if (otile == 0)      { Wsrc = Wq;                     bsrc = bq;      obase = 0; }
    else if (otile == 1) { Wsrc = Wk;                     bsrc = bk;      obase = 0; }
    else                 { Wsrc = Wv + (otile - 2) * 64 * Cn;
                           bsrc = bv + (otile - 2) * 64;  obase = (otile - 2) * 64; }

    for (int u = 0; u < 8; ++u) {
        int f = tid + u * 256;
        int row = f >> 5;
        int col = (f & 31) * 4;
        *(float4*)&Ws[row][col] = *(const float4*)&Wsrc[row * Cn + col];
    }
    const float* xb = x + ((size_t)b * Cn) * Nn + nbase;
    for (int u = 0; u < 8; ++u) {
        int f = tid + u * 256;
        int c = f >> 4;
        int n = (f & 15) * 4;
        *(float4*)&Xs[c][n] = *(const float4*)&xb[(size_t)c * Nn + n];
    }
    __syncthreads();

    const int o0 = (tid >> 4) * 4;
    const int n0 = (tid & 15) * 4;
    float acc[4][4] = {};

    for (int c = 0; c < Cn; c += 4) {
        float4 w4[4], x4[4];
        for (int oo = 0; oo < 4; ++oo) w4[oo] = *(const float4*)&Ws[o0 + oo][c];
        for (int cc = 0; cc < 4; ++cc) x4[cc] = *(const float4*)&Xs[c + cc][n0];
        for (int oo = 0; oo < 4; ++oo) {
            const float* wv = (const float*)&w4[oo];
            for (int cc = 0; cc < 4; ++cc) {
                const float wsv = wv[cc];
                const float* xp = (const float*)&x4[cc];
                acc[oo][0] += wsv * xp[0];
                acc[oo][1] += wsv * xp[1];
                acc[oo][2] += wsv * xp[2];
                acc[oo][3] += wsv * xp[3];
            }
        }
    }

    float bias[4];
    for (int oo = 0; oo < 4; ++oo) bias[oo] = bsrc[o0 + oo];

    union H4 { _Float16 e[4]; short4 v; };

    if (otile <= 1) {
        _Float16* dst = (otile == 0 ? Qh : Kh) + ((size_t)b * Nn + nbase) * CQn;
        for (int nn = 0; nn < 4; ++nn) {
            H4 h;
            for (int oo = 0; oo < 4; ++oo) h.e[oo] = (_Float16)(acc[oo][nn] + bias[oo]);
            *(short4*)&dst[(size_t)(n0 + nn) * CQn + o0] = h.v;
        }
    } else {
        // Vg[b][ntile][c][pos]
        _Float16* dst = Vg + (size_t)(b * 64 + ntile) * 128 * 64;
        const int og = obase + o0;
        const int a  = n0 >> 2;
        const int h  = a >> 3, qd = a & 7;
        const int pbase = h * 32 + (qd & 3) * 8 + (qd >> 2) * 4;
        for (int oo = 0; oo < 4; ++oo) {
            H4 hh;
            for (int nn = 0; nn < 4; ++nn) hh.e[nn] = (_Float16)(acc[oo][nn] + bias[oo]);
            *(short4*)&dst[(size_t)(og + oo) * 64 + pbase] = hh.v;
        }
    }
}

// ---------------------------------------------------------------------------
// Kernel 2: MFMA flash attention, KV split across blocks (grid z = s).
// Round-15: LDS 40->32 KB (K dbuf 2x8 KB + V SINGLE 16 KB). Round-14's
// 40 KB fit only 3 blocks/CU -> 1024-block grid ran 768 + 256-straggler
// (measured Occupancy 30.3% == 0.75*37.5 + 0.25*12.5). 32 KB -> >=4
// blocks/CU, grid = exactly 4/CU, zero tail, ~50% occupancy. Register
// structure unchanged from R14 (VGPR 60, zero spill).
// Schedule per tile (2 barriers, every stage covered):
//   stageK(t+1) at top (cover: scores+softmax ~500cy)
//   scores(t) [K LDS buf t&1] -> softmax
//   bar#1: drains V(t) [staged last tile] + K(t+1)
//   PV(t) [V LDS] -> bar#2 (V buffer free) -> stageV(t+1) (L2, ~300cy,
//   covered by next tile's scores+softmax).
// K XOR-swizzled b128 reads; V fragment-major (R12: 0 conflicts).
// Swapped QK^T (D=S^T, col=query=ln); kappa(e,g)=4g+(e&3)+16(e>>2) pairing.
// Defer-max (THR=8).
// ---------------------------------------------------------------------------
__device__ __forceinline__ void gload16(const void* g, void* l) {
    __builtin_amdgcn_global_load_lds(
        (const __attribute__((address_space(1))) u32*)g,
        (__attribute__((address_space(3))) u32*)l, 16, 0, 0);
}

#define KOFF0 0          // K buffer 0: 8 KB
#define KOFF1 8192       // K buffer 1: 8 KB
#define VOFF  16384      // V buffer: 16 KB (single)

__global__ __launch_bounds__(256) void attn_split(
    const _Float16* __restrict__ Qh, const _Float16* __restrict__ Kh,
    const _Float16* __restrict__ Vg, float* __restrict__ out,
    float* __restrict__ pPart, float* __restrict__ pMl, int S)
{
    __shared__ __align__(16) char smem[32768];

    const int tid  = threadIdx.x;
    const int w    = tid >> 6;
    const int lane = tid & 63;
    const int g    = lane >> 4;
    const int ln   = lane & 15;
    const int it   = blockIdx.x;
    const int b    = blockIdx.y;
    const int s    = blockIdx.z;
    const int wib  = it * 64 + w * 16;
    const int njt  = 64 / S;

    // Persistent Q fragments (B operand: col=ln -> query wib+ln)
    const _Float16* qrow = Qh + ((size_t)(b * Nn + wib + ln)) * CQn + 8 * g;
    const h8_t q0 = *(const h8_t*)(qrow);
    const h8_t q1 = *(const h8_t*)(qrow + 32);

    const _Float16* Kb  = Kh + (size_t)b * Nn * CQn;
    const _Float16* Vgb = Vg + (size_t)b * 64 * 8192;   // 64 tiles x 8192 f16

    // K staging source offsets (f16): granule G holds
    // K_tile[row=G>>3][((G&7)^(row&7))*8 .. +7]
    int ks[2];
    #pragma unroll
    for (int u = 0; u < 2; ++u) {
        int G   = u * 256 + tid;
        int row = G >> 3;
        ks[u] = row * CQn + (((G & 7) ^ (row & 7)) * 8);
    }
    // V staging source offsets (f16), fragment-major tile [128c][64pos]
    int vs[4];
    #pragma unroll
    for (int u = 0; u < 4; ++u) {
        int G   = u * 256 + tid;
        int row = G >> 3;
        vs[u] = row * 64 + (((G & 7) ^ (row & 7)) * 8);
    }

    // LDS read offsets (bytes), XOR r7 = ln&7
    const int r7  = ln & 7;
    const int kb0 = ln * 128 + (((    g) ^ r7) << 4);
    const int kb1 = ln * 128 + (((4 + g) ^ r7) << 4);

    auto stageK = [&](int koff, int jt) {
        const _Float16* src = Kb + (size_t)jt * 64 * CQn;
        #pragma unroll
        for (int u = 0; u < 2; ++u)
            gload16(src + ks[u], smem + koff + u * 4096 + w * 1024);
    };
    auto stageV = [&](int jt) {
        const _Float16* src = Vgb + (size_t)jt * 8192;
        #pragma unroll
        for (int u = 0; u < 4; ++u)
            gload16(src + vs[u], smem + VOFF + u * 4096 + w * 1024);
    };

    f32x4 oacc[8];
    #pragma unroll
    for (int i = 0; i < 8; ++i) oacc[i] = (f32x4){0.f, 0.f, 0.f, 0.f};
    float m_run = -3.0e38f, l_run = 0.f;

    const int jt0 = s * njt;
    stageK(KOFF0, jt0);
    stageV(jt0);
    __syncthreads();

    for (int t = 0; t < njt; ++t) {
        // 1) stage next K tile into the other K buffer (drains at bar#1)
        if (t + 1 < njt) stageK((t & 1) ? KOFF0 : KOFF1, jt0 + t + 1);

        // 2) scores from K LDS: st[js] rows = keys js*16+4g+r, col = query ln
        const char* KU = smem + ((t & 1) ? KOFF1 : KOFF0);
        f32x4 st[4];
        __builtin_amdgcn_s_setprio(1);
        #pragma unroll
        for (int js = 0; js < 4; ++js) {
            h8_t k0 = *(const h8_t*)(KU + kb0 + js * 2048);
            h8_t k1 = *(const h8_t*)(KU + kb1 + js * 2048);
            st[js] = (f32x4){0.f, 0.f, 0.f, 0.f};
            st[js] = __builtin_amdgcn_mfma_f32_16x16x32_f16(k0, q0, st[js], 0, 0, 0);
            st[js] = __builtin_amdgcn_mfma_f32_16x16x32_f16(k1, q1, st[js], 0, 0, 0);
        }
        __builtin_amdgcn_s_setprio(0);

        // 3) online softmax with defer-max (THR=8)
        float tmax = st[0][0];
        #pragma unroll
        for (int js = 0; js < 4; ++js)
            #pragma unroll
            for (int r = 0; r < 4; ++r) tmax = fmaxf(tmax, st[js][r]);
        tmax = fmaxf(tmax, __shfl_xor(tmax, 16));
        tmax = fmaxf(tmax, __shfl_xor(tmax, 32));
        if (__any(tmax > m_run + 8.f)) {
            const float mnew  = fmaxf(m_run, tmax);
            const float alpha = __expf(m_run - mnew);
            const float a0 = __shfl(alpha, 4 * g + 0);
            const float a1 = __shfl(alpha, 4 * g + 1);
            const float a2 = __shfl(alpha, 4 * g + 2);
            const float a3 = __shfl(alpha, 4 * g + 3);
            #pragma unroll
            for (int cs = 0; cs < 8; ++cs) {
                oacc[cs][0] *= a0; oacc[cs][1] *= a1;
                oacc[cs][2] *= a2; oacc[cs][3] *= a3;
            }
            l_run *= alpha;
            m_run = mnew;
        }
        float ts = 0.f;
        #pragma unroll
        for (int js = 0; js < 4; ++js)
            #pragma unroll
            for (int r = 0; r < 4; ++r) {
                float p = __expf(st[js][r] - m_run);
                st[js][r] = p;
                ts += p;
            }
        ts += __shfl_xor(ts, 16);
        ts += __shfl_xor(ts, 32);
        l_run += ts;

        // 4) P fragments by kappa(e,g) = 4g+(e&3)+16*(e>>2)
        union H8 { h8_t h; _Float16 e[8]; };
        H8 p0u, p1u;
        #pragma unroll
        for (int r = 0; r < 4; ++r) {
            p0u.e[r]     = (_Float16)st[0][r];
            p0u.e[4 + r] = (_Float16)st[1][r];
            p1u.e[r]     = (_Float16)st[2][r];
            p1u.e[4 + r] = (_Float16)st[3][r];
        }
        const h8_t pa0 = p0u.h;
        const h8_t pa1 = p1u.h;

        __syncthreads();   // bar#1: drains V(t) stage + K(t+1) stage

        // 5) PV: fragment-major V from LDS, one b128 per (cs, half)
        __builtin_amdgcn_s_setprio(1);
        #pragma unroll
        for (int cs = 0; cs < 8; ++cs) {
            h8_t v01 = *(const h8_t*)(smem + VOFF + kb0 + cs * 2048);
            h8_t v23 = *(const h8_t*)(smem + VOFF + kb1 + cs * 2048);
            oacc[cs] = __builtin_amdgcn_mfma_f32_16x16x32_f16(pa0, v01, oacc[cs], 0, 0, 0);
            oacc[cs] = __builtin_amdgcn_mfma_f32_16x16x32_f16(pa1, v23, oacc[cs], 0, 0, 0);
        }
        __builtin_amdgcn_s_setprio(0);

        __syncthreads();   // bar#2: all waves done reading V(t) -> buffer free

        // 6) stage V(t+1) into the freed buffer (drains at next bar#1,
        //    covered by next tile's scores+softmax; Vg is L2-resident)
        if (t + 1 < njt) stageV(jt0 + t + 1);
    }

    if (S == 1) {
        const float lr = 1.f / l_run;
        const float l0 = __shfl(lr, 4 * g + 0);
        const float l1 = __shfl(lr, 4 * g + 1);
        const float l2 = __shfl(lr, 4 * g + 2);
        const float l3 = __shfl(lr, 4 * g + 3);
        float* ob = out + (size_t)b * Cn * Nn;
        #pragma unroll
        for (int cs = 0; cs < 8; ++cs) {
            float4 o;
            o.x = oacc[cs][0] * l0;
            o.y = oacc[cs][1] * l1;
            o.z = oacc[cs][2] * l2;
            o.w = oacc[cs][3] * l3;
            *(float4*)&ob[(size_t)(cs * 16 + ln) * Nn + wib + 4 * g] = o;
        }
    } else {
        float* pp = pPart + (((size_t)b * 64 + it) * S + s) * 8192;
        const int qloc = w * 16 + 4 * g;
        #pragma unroll
        for (int cs = 0; cs < 8; ++cs)
            *(float4*)&pp[(size_t)(cs * 16 + ln) * 64 + qloc] =
                make_float4(oacc[cs][0], oacc[cs][1], oacc[cs][2], oacc[cs][3]);
        if (g == 0) {
            float* ml = pMl + ((((size_t)b * 64 + it) * S + s) * 64 + w * 16 + ln) * 2;
            ml[0] = m_run;
            ml[1] = l_run;
        }
    }
}

// ---------------------------------------------------------------------------
// Kernel 3: flash-combine across S splits. Grid (64 it, B), 256 threads.
// ---------------------------------------------------------------------------
__global__ __launch_bounds__(256) void attn_combine(
    const float* __restrict__ pPart, const float* __restrict__ pMl,
    float* __restrict__ out, int S)
{
    const int it  = blockIdx.x;
    const int b   = blockIdx.y;
    const int tid = threadIdx.x;

    __shared__ float wgt[4][64];
    __shared__ float linv[64];

    if (tid < 64) {
        const float* mlb = pMl + (((size_t)b * 64 + it) * S * 64 + tid) * 2;
        float ms[4], ls[4], m = -3.0e38f;
        for (int s = 0; s < S; ++s) {
            ms[s] = mlb[s * 128 + 0];
            ls[s] = mlb[s * 128 + 1];
            m = fmaxf(m, ms[s]);
        }
        float l = 0.f;
        for (int s = 0; s < S; ++s) {
            float wv = __expf(ms[s] - m);
            wgt[s][tid] = wv;
            l += wv * ls[s];
        }
        linv[tid] = 1.f / l;
    }
    __syncthreads();

    const int c  = tid >> 1;
    const int q0 = (tid & 1) * 32;
    const float* base = pPart + ((size_t)b * 64 + it) * S * 8192 + (size_t)c * 64 + q0;

    float acc[32];
    #pragma unroll
    for (int k = 0; k < 32; ++k) acc[k] = 0.f;
    for (int s = 0; s < S; ++s) {
        const float* ps = base + (size_t)s * 8192;
        #pragma unroll
        for (int k = 0; k < 32; k += 4) {
            float4 v = *(const float4*)(ps + k);
            acc[k + 0] += wgt[s][q0 + k + 0] * v.x;
            acc[k + 1] += wgt[s][q0 + k + 1] * v.y;
            acc[k + 2] += wgt[s][q0 + k + 2] * v.z;
            acc[k + 3] += wgt[s][q0 + k + 3] * v.w;
        }
    }
    float* ob = out + ((size_t)b * Cn + c) * Nn + it * 64 + q0;
    #pragma unroll
    for (int k = 0; k < 32; k += 4) {
        float4 o;
        o.x = acc[k + 0] * linv[q0 + k + 0];
        o.y = acc[k + 1] * linv[q0 + k + 1];
        o.z = acc[k + 2] * linv[q0 + k + 2];
        o.w = acc[k + 3] * linv[q0 + k + 3];
        *(float4*)&ob[k] = o;
    }
}

extern "C" void kernel_launch(void* const* d_in, const int* in_sizes, int n_in,
                              void* d_out, int out_size, void* d_ws, size_t ws_size,
                              hipStream_t stream) {
    const float* x  = (const float*)d_in[0];
    const float* Wq = (const float*)d_in[1];
    const float* bq = (const float*)d_in[2];
    const float* Wk = (const float*)d_in[3];
    const float* bk = (const float*)d_in[4];
    const float* Wv = (const float*)d_in[5];
    const float* bv = (const float*)d_in[6];
    float* out = (float*)d_out;

    _Float16* ws = (_Float16*)d_ws;
    _Float16* Qh = ws;
    _Float16* Kh = ws + 1048576;
    _Float16* Vg = ws + 2097152;

    int S = 1;
    if (ws_size >= QKV_BYTES + 4 * (PART_PER_S + ML_PER_S)) S = 4;
    else if (ws_size >= QKV_BYTES + 2 * (PART_PER_S + ML_PER_S)) S = 2;

    float* pPart = (float*)((char*)d_ws + QKV_BYTES);
    float* pMl   = (float*)((char*)d_ws + QKV_BYTES + (size_t)S * PART_PER_S);

    dim3 gproj(Nn / 64, 4, Bn);
    qkv_proj<<<gproj, 256, 0, stream>>>(x, Wq, bq, Wk, bk, Wv, bv, Qh, Kh, Vg);

    dim3 gattn(Nn / 64, Bn, S);
    attn_split<<<gattn, 256, 0, stream>>>(Qh, Kh, Vg, out, pPart, pMl, S);

    if (S > 1) {
        dim3 gcomb(Nn / 64, Bn);
        attn_combine<<<gcomb, 256, 0, stream>>>(pPart, pMl, out, S);
    }
}